// Round 7
// baseline (18139.124 us; speedup 1.0000x reference)
//
#include <hip/hip_runtime.h>
#include <hip/hip_bf16.h>
#include <stdint.h>

// Decoder: 2-layer LSTM, B=2048, T=96, H=1024, teacher forcing=1.0.
// Round 7: PERSISTENT cooperative kernel. 256 blocks (1/CU) x 512 thr, fixed
// (mode,tm,tn) per block for all 96 steps. c-state in LDS for the whole run.
// One device-wide generation barrier per step. GEMM: 256x256 tile, BK=32,
// dbuf LDS, both-sides XOR swizzle, incremental src pointers, setprio.

#define BB  2048
#define TT  96
#define NG  4096
#define KL1 1088      // [h1 1024 | x 60 | pad 4]   (h1 FIRST for incremental addressing)
#define KL2 2048      // [h1 | h2]
#define NBLK 256

typedef __bf16 bf16;
typedef __bf16 bf16x8 __attribute__((ext_vector_type(8)));
typedef float  f32x4  __attribute__((ext_vector_type(4)));

__device__ __forceinline__ float sigm(float x) { return 1.0f / (1.0f + __expf(-x)); }

__device__ __forceinline__ void gload16(const bf16* g, bf16* l) {
  __builtin_amdgcn_global_load_lds((const __attribute__((address_space(1))) void*)g,
                                   (__attribute__((address_space(3))) void*)l, 16, 0, 0);
}

#define SB()  __builtin_amdgcn_sched_barrier(0)
#define BAR() __builtin_amdgcn_s_barrier()
#define WAITV0() asm volatile("s_waitcnt vmcnt(0)" ::: "memory")
#define WAITL0() asm volatile("s_waitcnt lgkmcnt(0)" ::: "memory")

// device-wide generation barrier (blocks guaranteed co-resident via cooperative launch)
__device__ __forceinline__ void gsync(int* cnt, int* gen) {
  __threadfence();                 // release: publish H writes device-wide
  __syncthreads();
  if (threadIdx.x == 0) {
    int g = __hip_atomic_load(gen, __ATOMIC_RELAXED, __HIP_MEMORY_SCOPE_AGENT);
    if (__hip_atomic_fetch_add(cnt, 1, __ATOMIC_ACQ_REL, __HIP_MEMORY_SCOPE_AGENT) == NBLK - 1) {
      __hip_atomic_store(cnt, 0, __ATOMIC_RELAXED, __HIP_MEMORY_SCOPE_AGENT);
      __hip_atomic_fetch_add(gen, 1, __ATOMIC_RELEASE, __HIP_MEMORY_SCOPE_AGENT);
    } else {
      while (__hip_atomic_load(gen, __ATOMIC_RELAXED, __HIP_MEMORY_SCOPE_AGENT) == g)
        __builtin_amdgcn_s_sleep(2);
    }
  }
  __syncthreads();
  __threadfence();                 // acquire: invalidate stale cached lines
}

// ---------------- prep kernels ----------------
// Weight rows permuted: out row n' = h*4 + gate  <-  in row gate*1024 + h.
// W0 k-layout: [Whh0 (1024) | Wih0 (60) | pad (4)]

__global__ __launch_bounds__(256) void build_w0(const float* __restrict__ Wih0,
                                                const float* __restrict__ Whh0,
                                                bf16* __restrict__ W0) {
  int idx = blockIdx.x * 256 + threadIdx.x;
  if (idx >= NG * KL1) return;
  int np = idx / KL1, k = idx % KL1;
  int n = (np & 3) * 1024 + (np >> 2);
  float v;
  if (k < 1024)      v = Whh0[n * 1024 + k];
  else if (k < 1084) v = Wih0[n * 60 + (k - 1024)];
  else               v = 0.0f;
  W0[idx] = (bf16)v;
}

__global__ __launch_bounds__(256) void build_w1(const float* __restrict__ Wih1,
                                                const float* __restrict__ Whh1,
                                                bf16* __restrict__ W1) {
  int idx = blockIdx.x * 256 + threadIdx.x;
  if (idx >= NG * KL2) return;
  int np = idx >> 11, k = idx & 2047;
  int n = (np & 3) * 1024 + (np >> 2);
  float v = (k < 1024) ? Wih1[n * 1024 + k] : Whh1[n * 1024 + (k - 1024)];
  W1[idx] = (bf16)v;
}

__global__ __launch_bounds__(256) void perm_bias(const float* __restrict__ b0,
                                                 const float* __restrict__ b1,
                                                 float* __restrict__ b0p,
                                                 float* __restrict__ b1p) {
  int idx = blockIdx.x * 256 + threadIdx.x;
  if (idx >= NG) return;
  int n = (idx & 3) * 1024 + (idx >> 2);
  b0p[idx] = b0[n];
  b1p[idx] = b1[n];
}

// X2 layout: [t][b][64]; x[60..63] = 0
__global__ __launch_bounds__(256) void build_x2(
    const float* __restrict__ dec, const float* __restrict__ ty, const float* __restrict__ lec,
    const int* __restrict__ gid, const int* __restrict__ cp, const int* __restrict__ cct,
    const int* __restrict__ cpt, const int* __restrict__ ccl,
    const float* __restrict__ gemb, const float* __restrict__ ep, const float* __restrict__ ect,
    const float* __restrict__ ept, const float* __restrict__ ecl,
    bf16* __restrict__ X2) {
  int idx = blockIdx.x * 256 + threadIdx.x;  // over T*B
  if (idx >= BB * TT) return;
  int t = idx >> 11, b = idx & 2047;
  bf16* x = X2 + (size_t)idx * 64;
  x[0] = (bf16)((t == 0) ? lec[b] : ty[b * TT + t - 1]);
  const float* d = dec + ((size_t)b * TT + t) * 32;
  #pragma unroll
  for (int k = 0; k < 32; ++k) x[1 + k] = (bf16)d[k];
  const float* e;
  e = ep  + cp[b]  * 4;  for (int j = 0; j < 4;  ++j) x[33 + j] = (bf16)e[j];
  e = ect + cct[b] * 2;  for (int j = 0; j < 2;  ++j) x[37 + j] = (bf16)e[j];
  e = ept + cpt[b] * 3;  for (int j = 0; j < 3;  ++j) x[39 + j] = (bf16)e[j];
  e = ecl + ccl[b] * 2;  for (int j = 0; j < 2;  ++j) x[42 + j] = (bf16)e[j];
  e = gemb + gid[b] * 16; for (int j = 0; j < 16; ++j) x[44 + j] = (bf16)e[j];
  for (int j = 60; j < 64; ++j) x[j] = (bf16)0.0f;
}

// enc state -> H1[1], H2[1] (parity of t=-1) and transposed c ([h][b]) staging
__global__ __launch_bounds__(256) void init_state(const float* __restrict__ enc_h,
                                                  const float* __restrict__ enc_c,
                                                  bf16* __restrict__ H1b,
                                                  bf16* __restrict__ H2b,
                                                  float* __restrict__ c1t,
                                                  float* __restrict__ c2t) {
  int idx = blockIdx.x * 256 + threadIdx.x;  // over B*H
  if (idx >= BB * 1024) return;
  int b = idx >> 10, h = idx & 1023;
  H1b[idx] = (bf16)enc_h[idx];
  H2b[idx] = (bf16)enc_h[(size_t)BB * 1024 + idx];
  c1t[(size_t)h * BB + b] = enc_c[idx];
  c2t[(size_t)h * BB + b] = enc_c[(size_t)BB * 1024 + idx];
}

// ---------------- fused GEMM + cell (one timestep, one 256x256 tile) ----------------
// gates(b, n') = A(b,:) . W(n',:), n' = h*4 + gate. mfma(W_frag, A_frag):
// lane's f32x4 = {i,f,g,o} of one (b,h) cell.
// K split: tiles 0..31 from PA (row stride 1024); tiles 32.. from PB
// (MODE0: X2 row stride 64; MODE1: h2 row stride 1024).
// LDS swizzle: stored 16B-slot s at row r holds source k-slot s ^ ((r>>1)&3).

template <int MODE>
__device__ __forceinline__ void body(
    int tm, int tn, bf16* stg, float* c_lds,
    const bf16* __restrict__ PA, const bf16* __restrict__ PB,
    const bf16* __restrict__ Wt, const float* __restrict__ bperm,
    bf16* __restrict__ Hout, const float* __restrict__ wp,
    float* __restrict__ y, int t)
{
  constexpr int KT = MODE ? KL2 : KL1;
  constexpr int NT = KT / 32;          // 64 / 34

  const int tid = threadIdx.x;
  const int lane = tid & 63, w = tid >> 6;
  const int l15 = lane & 15, u = lane >> 4;
  const int wq = w & 3, wbh = w >> 2;

  f32x4 acc[8][4];
  #pragma unroll
  for (int i = 0; i < 8; ++i)
    #pragma unroll
    for (int j = 0; j < 4; ++j) acc[i][j] = (f32x4){0.f, 0.f, 0.f, 0.f};

  // staging geometry: slots s0=tid, s1=512+tid -> row=s>>2, stored kslot=s&3
  const int r0 = tid >> 2, r1 = (512 + tid) >> 2;
  const int kc0 = (((tid & 3) ^ ((r0 >> 1) & 3)) << 3);     // source k elems (swizzled)
  const int kc1 = (((tid & 3) ^ ((r1 >> 1) & 3)) << 3);
  const int dof = tid * 8;                                  // LDS dest elems (linear)

  // incremental per-thread source pointers (advance 32 elems/tile)
  const bf16* pa0 = PA + (size_t)(tm + r0) * 1024 + kc0;
  const bf16* pa1 = PA + (size_t)(tm + r1) * 1024 + kc1;
  const bf16* pb0;
  const bf16* pb1;
  if constexpr (MODE == 0) {
    pb0 = PB + (size_t)(tm + r0) * 64 + kc0;
    pb1 = PB + (size_t)(tm + r1) * 64 + kc1;
  } else {
    pb0 = PB + (size_t)(tm + r0) * 1024 + kc0;
    pb1 = PB + (size_t)(tm + r1) * 1024 + kc1;
  }
  const bf16* pw0 = Wt + (size_t)(tn + r0) * KT + kc0;
  const bf16* pw1 = Wt + (size_t)(tn + r1) * KT + kc1;

  auto stage = [&](int buf, int kt) {
    const bf16 *a0, *a1;
    if (kt < 32) { a0 = pa0 + kt * 32;        a1 = pa1 + kt * 32; }
    else         { a0 = pb0 + (kt - 32) * 32; a1 = pb1 + (kt - 32) * 32; }
    bf16* dA = stg + buf * 8192;
    bf16* dW = stg + 16384 + buf * 8192;
    gload16(a0, dA + dof);
    gload16(a1, dA + 4096 + dof);
    gload16(pw0 + kt * 32, dW + dof);
    gload16(pw1 + kt * 32, dW + 4096 + dof);
  };

  // read geometry
  const int klocal = (((u ^ (l15 >> 1)) & 3) << 3);
  const int aoffA = (wbh * 128 + l15) * 32 + klocal;
  const int aoffW = (wq * 64 + l15) * 32 + klocal;

  stage(0, 0);   // prologue

  for (int kt = 0; kt < NT; ++kt) {
    const int buf = kt & 1;
    WAITV0(); SB(); BAR(); SB();
    if (kt + 1 < NT) stage(buf ^ 1, kt + 1);
    SB();
    __builtin_amdgcn_s_setprio(1);
    bf16x8 a_[8], w_[4];
    #pragma unroll
    for (int mf = 0; mf < 8; ++mf)
      a_[mf] = *reinterpret_cast<const bf16x8*>(stg + buf * 8192 + aoffA + mf * 512);
    #pragma unroll
    for (int gf = 0; gf < 4; ++gf)
      w_[gf] = *reinterpret_cast<const bf16x8*>(stg + 16384 + buf * 8192 + aoffW + gf * 512);
    #pragma unroll
    for (int mf = 0; mf < 8; ++mf)
      #pragma unroll
      for (int gf = 0; gf < 4; ++gf)
        acc[mf][gf] = __builtin_amdgcn_mfma_f32_16x16x32_bf16(w_[gf], a_[mf], acc[mf][gf], 0, 0, 0);
    __builtin_amdgcn_s_setprio(0);
  }

  SB(); BAR(); SB();   // all K-loop LDS reads done -> staging reusable

  // ---- fused cell epilogue (c in LDS, padded row 260) ----
  bf16* hst = stg + w * 3072;          // per-wave [128 b][24-pad 16 h]
  const int hb0 = tn >> 2;
  const int hbw = wq * 16;
  const int bgb = tm + wbh * 128;
  float yp[8] = {0.f, 0.f, 0.f, 0.f, 0.f, 0.f, 0.f, 0.f};

  #pragma unroll
  for (int gf = 0; gf < 4; ++gf) {
    int lh = hbw + gf * 4 + u;         // local h (0..63)
    int hg = hb0 + lh;                 // global h
    f32x4 bv = *reinterpret_cast<const f32x4*>(&bperm[hg * 4]);
    float wph = 0.f;
    if constexpr (MODE == 1) wph = wp[hg];
    #pragma unroll
    for (int bf = 0; bf < 8; ++bf) {
      int lb = wbh * 128 + bf * 16 + l15;
      float gi = acc[bf][gf][0] + bv[0];
      float gf_ = acc[bf][gf][1] + bv[1];
      float gg = acc[bf][gf][2] + bv[2];
      float go = acc[bf][gf][3] + bv[3];
      float* cp_ = &c_lds[lh * 260 + lb];
      float c = *cp_;
      float cn = sigm(gf_) * c + sigm(gi) * tanhf(gg);
      float hn = sigm(go) * tanhf(cn);
      *cp_ = cn;
      hst[(bf * 16 + l15) * 24 + gf * 4 + u] = (bf16)hn;
      if constexpr (MODE == 1) yp[bf] += hn * wph;
    }
  }

  WAITL0(); SB();

  // coalesced H write: wave patch = 128 batch x 16 h
  #pragma unroll
  for (int q = 0; q < 4; ++q) {
    int chunk = q * 64 + lane;
    int row = chunk >> 1, h8 = chunk & 1;
    bf16x8 v = *reinterpret_cast<const bf16x8*>(&hst[row * 24 + h8 * 8]);
    *reinterpret_cast<bf16x8*>(&Hout[(size_t)(bgb + row) * 1024 + hb0 + hbw + h8 * 8]) = v;
  }

  if constexpr (MODE == 1) {
    #pragma unroll
    for (int bf = 0; bf < 8; ++bf) {
      float s = yp[bf];
      s += __shfl_xor(s, 16);
      s += __shfl_xor(s, 32);
      if (lane < 16)
        atomicAdd(&y[(size_t)(bgb + bf * 16 + lane) * TT + t], s);
    }
  }
}

// ---------------- persistent kernel ----------------
// 256 blocks: x=bid&7 (XCD), i=bid>>3: mode=i&1, tm=(i>>2)*256,
// tn=(x*2+((i>>1)&1))*256. mode0 blocks do L1(t+1), mode1 do L2(t).
__global__ __launch_bounds__(512, 2) void lstm_persist(
    bf16* H1a, bf16* H1b, bf16* H2a, bf16* H2b,
    const bf16* X2, const bf16* W0, const bf16* W1,
    const float* b0p, const float* b1p,
    const float* c1t, const float* c2t,
    const float* wp, const float* bp, float* y,
    int* cnt, int* gen)
{
  __shared__ alignas(16) bf16 stg[32768];       // 64 KB: A [0,16K), W [16K,32K)
  __shared__ float c_lds[64 * 260];             // 66.6 KB, padded rows

  const int bid = (int)blockIdx.x;
  const int x = bid & 7, i = bid >> 3;
  const int mode = i & 1;
  const int tm = (i >> 2) << 8;
  const int tn = (((x << 1) + ((i >> 1) & 1))) << 8;
  const int tid = threadIdx.x;

  // load this block's c tile into LDS (coalesced; [h][b] source layout)
  const float* ct = mode ? c2t : c1t;
  const int hb0 = tn >> 2;
  for (int k = tid; k < 16384; k += 512)
    c_lds[(k >> 8) * 260 + (k & 255)] = ct[(size_t)(hb0 + (k >> 8)) * BB + tm + (k & 255)];

  // init y = b_proj (once, by the 8 mode0/tn==0 blocks)
  if (mode == 0 && tn == 0) {
    float bpv = bp[0];
    for (int k = tid; k < 256 * TT; k += 512) y[(size_t)tm * TT + k] = bpv;
  }

  gsync(cnt, gen);

  // prologue: h1(0) = LSTM1(x(0), h1(-1)=H1b)
  if (mode == 0)
    body<0>(tm, tn, stg, c_lds, H1b, X2, W0, b0p, H1a, wp, y, 0);
  gsync(cnt, gen);

  for (int t = 0; t < TT; ++t) {
    const bf16* h1cur = (t & 1) ? H1b : H1a;        // h1(t)
    if (mode == 1) {
      const bf16* h2prev = (t & 1) ? H2a : H2b;     // h2(t-1)
      bf16* h2out = (t & 1) ? H2b : H2a;            // h2(t)
      body<1>(tm, tn, stg, c_lds, h1cur, h2prev, W1, b1p, h2out, wp, y, t);
    } else if (t + 1 < TT) {
      bf16* h1out = (t & 1) ? H1a : H1b;            // h1(t+1)
      body<0>(tm, tn, stg, c_lds, h1cur, X2 + (size_t)(t + 1) * BB * 64, W0, b0p, h1out, wp, y, t + 1);
    }
    gsync(cnt, gen);
  }
}

// ---------------- launch ----------------

extern "C" void kernel_launch(void* const* d_in, const int* in_sizes, int n_in,
                              void* d_out, int out_size, void* d_ws, size_t ws_size,
                              hipStream_t stream) {
  const float* dec   = (const float*)d_in[0];
  const float* ty    = (const float*)d_in[1];
  const float* enc_h = (const float*)d_in[2];
  const float* enc_c = (const float*)d_in[3];
  const float* lec   = (const float*)d_in[4];
  const int*   gid   = (const int*)d_in[5];
  const int*   cp    = (const int*)d_in[6];
  const int*   cct   = (const int*)d_in[7];
  const int*   cpt   = (const int*)d_in[8];
  const int*   ccl   = (const int*)d_in[9];
  const float* gemb  = (const float*)d_in[10];
  const float* ep    = (const float*)d_in[11];
  const float* ect   = (const float*)d_in[12];
  const float* ept   = (const float*)d_in[13];
  const float* ecl   = (const float*)d_in[14];
  const float* Wih0  = (const float*)d_in[15];
  const float* Whh0  = (const float*)d_in[16];
  const float* b0    = (const float*)d_in[17];
  const float* Wih1  = (const float*)d_in[18];
  const float* Whh1  = (const float*)d_in[19];
  const float* b1    = (const float*)d_in[20];
  const float* wp    = (const float*)d_in[21];
  const float* bp    = (const float*)d_in[22];
  float* y = (float*)d_out;

  char* ws = (char*)d_ws;
  bf16* W0    = (bf16*)ws;  ws += (size_t)NG * KL1 * 2;      //  8.9 MB
  bf16* W1    = (bf16*)ws;  ws += (size_t)NG * KL2 * 2;      // 16.8 MB
  bf16* X2    = (bf16*)ws;  ws += (size_t)BB * TT * 64 * 2;  // 25.2 MB
  bf16* H1a   = (bf16*)ws;  ws += (size_t)BB * 1024 * 2;     //  4.2 MB each
  bf16* H1b   = (bf16*)ws;  ws += (size_t)BB * 1024 * 2;
  bf16* H2a   = (bf16*)ws;  ws += (size_t)BB * 1024 * 2;
  bf16* H2b   = (bf16*)ws;  ws += (size_t)BB * 1024 * 2;
  float* c1t  = (float*)ws; ws += (size_t)BB * 1024 * 4;     //  8.4 MB
  float* c2t  = (float*)ws; ws += (size_t)BB * 1024 * 4;     //  8.4 MB
  float* b0p  = (float*)ws; ws += (size_t)NG * 4;
  float* b1p  = (float*)ws; ws += (size_t)NG * 4;
  int* flags  = (int*)ws;   ws += 256;                       // cnt, gen

  build_w0<<<(NG * KL1 + 255) / 256, 256, 0, stream>>>(Wih0, Whh0, W0);
  build_w1<<<(NG * KL2 + 255) / 256, 256, 0, stream>>>(Wih1, Whh1, W1);
  perm_bias<<<NG / 256, 256, 0, stream>>>(b0, b1, b0p, b1p);
  build_x2<<<(BB * TT + 255) / 256, 256, 0, stream>>>(dec, ty, lec, gid, cp, cct, cpt, ccl,
                                                      gemb, ep, ect, ept, ecl, X2);
  init_state<<<(BB * 1024) / 256, 256, 0, stream>>>(enc_h, enc_c, H1b, H2b, c1t, c2t);
  hipMemsetAsync(flags, 0, 8, stream);

  int* cnt = flags;
  int* gen = flags + 1;
  void* args[] = {&H1a, &H1b, &H2a, &H2b, (void*)&X2, (void*)&W0, (void*)&W1,
                  (void*)&b0p, (void*)&b1p, (void*)&c1t, (void*)&c2t,
                  (void*)&wp, (void*)&bp, &y, &cnt, &gen};
  hipLaunchCooperativeKernel((const void*)lstm_persist, dim3(NBLK), dim3(512),
                             args, 0, stream);
}

// Round 8
// 7477.290 us; speedup vs baseline: 2.4259x; 2.4259x over previous
//
#include <hip/hip_runtime.h>
#include <hip/hip_bf16.h>
#include <stdint.h>

// Decoder: 2-layer LSTM, B=2048, T=96, H=1024, teacher forcing=1.0.
// Round 8: R3 base (best), + balanced 768-block grid (L1 blocks do 2 tn tiles
// => block durations equalized, no half-occupancy tail), + R4's corrected
// 2-way bank swizzle, + setprio. D_t = {L2(t) || L1(t+1)}, 3 blocks/CU.

#define BB  2048
#define TT  96
#define NG  4096
#define KL1 1088      // 64 (x pad) + 1024 (h1)
#define KL2 2048      // h1 | h2

typedef __bf16 bf16;
typedef __bf16 bf16x8 __attribute__((ext_vector_type(8)));
typedef float  f32x4  __attribute__((ext_vector_type(4)));

__device__ __forceinline__ float sigm(float x) { return 1.0f / (1.0f + __expf(-x)); }

__device__ __forceinline__ void gload16(const bf16* g, bf16* l) {
  __builtin_amdgcn_global_load_lds((const __attribute__((address_space(1))) void*)g,
                                   (__attribute__((address_space(3))) void*)l, 16, 0, 0);
}

#define SB() __builtin_amdgcn_sched_barrier(0)

// ---------------- prep kernels ----------------
// Weight rows permuted: out row n' = h*4 + gate  <-  in row gate*1024 + h.

__global__ __launch_bounds__(256) void build_w0(const float* __restrict__ Wih0,
                                                const float* __restrict__ Whh0,
                                                bf16* __restrict__ W0) {
  int idx = blockIdx.x * 256 + threadIdx.x;
  if (idx >= NG * KL1) return;
  int np = idx / KL1, k = idx % KL1;
  int n = (np & 3) * 1024 + (np >> 2);
  float v;
  if (k < 60)       v = Wih0[n * 60 + k];
  else if (k < 64)  v = 0.0f;
  else              v = Whh0[n * 1024 + (k - 64)];
  W0[idx] = (bf16)v;
}

__global__ __launch_bounds__(256) void build_w1(const float* __restrict__ Wih1,
                                                const float* __restrict__ Whh1,
                                                bf16* __restrict__ W1) {
  int idx = blockIdx.x * 256 + threadIdx.x;
  if (idx >= NG * KL2) return;
  int np = idx >> 11, k = idx & 2047;
  int n = (np & 3) * 1024 + (np >> 2);
  float v = (k < 1024) ? Wih1[n * 1024 + k] : Whh1[n * 1024 + (k - 1024)];
  W1[idx] = (bf16)v;
}

__global__ __launch_bounds__(256) void perm_bias(const float* __restrict__ b0,
                                                 const float* __restrict__ b1,
                                                 float* __restrict__ b0p,
                                                 float* __restrict__ b1p) {
  int idx = blockIdx.x * 256 + threadIdx.x;
  if (idx >= NG) return;
  int n = (idx & 3) * 1024 + (idx >> 2);
  b0p[idx] = b0[n];
  b1p[idx] = b1[n];
}

// X layout: [b][t][64]
__global__ __launch_bounds__(256) void build_x(
    const float* __restrict__ dec, const float* __restrict__ ty, const float* __restrict__ lec,
    const int* __restrict__ gid, const int* __restrict__ cp, const int* __restrict__ cct,
    const int* __restrict__ cpt, const int* __restrict__ ccl,
    const float* __restrict__ gemb, const float* __restrict__ ep, const float* __restrict__ ect,
    const float* __restrict__ ept, const float* __restrict__ ecl,
    bf16* __restrict__ X) {
  int idx = blockIdx.x * 256 + threadIdx.x;  // over B*T
  if (idx >= BB * TT) return;
  int b = idx / TT, t = idx % TT;
  bf16* x = X + (size_t)idx * 64;
  x[0] = (bf16)((t == 0) ? lec[b] : ty[b * TT + t - 1]);
  const float* d = dec + (size_t)idx * 32;
  #pragma unroll
  for (int k = 0; k < 32; ++k) x[1 + k] = (bf16)d[k];
  const float* e;
  e = ep  + cp[b]  * 4;  for (int j = 0; j < 4;  ++j) x[33 + j] = (bf16)e[j];
  e = ect + cct[b] * 2;  for (int j = 0; j < 2;  ++j) x[37 + j] = (bf16)e[j];
  e = ept + cpt[b] * 3;  for (int j = 0; j < 3;  ++j) x[39 + j] = (bf16)e[j];
  e = ecl + ccl[b] * 2;  for (int j = 0; j < 2;  ++j) x[42 + j] = (bf16)e[j];
  e = gemb + gid[b] * 16; for (int j = 0; j < 16; ++j) x[44 + j] = (bf16)e[j];
  for (int j = 60; j < 64; ++j) x[j] = (bf16)0.0f;
}

__global__ __launch_bounds__(256) void init_state(const float* __restrict__ enc_h,
                                                  const float* __restrict__ enc_c,
                                                  bf16* __restrict__ H1b,
                                                  bf16* __restrict__ H2b,
                                                  float* __restrict__ c1t,
                                                  float* __restrict__ c2t) {
  int idx = blockIdx.x * 256 + threadIdx.x;  // over B*H
  if (idx >= BB * 1024) return;
  int b = idx >> 10, h = idx & 1023;
  H1b[idx] = (bf16)enc_h[idx];
  H2b[idx] = (bf16)enc_h[(size_t)BB * 1024 + idx];
  c1t[(size_t)h * BB + b] = enc_c[idx];
  c2t[(size_t)h * BB + b] = enc_c[(size_t)BB * 1024 + idx];
}

// ---------------- fused GEMM + cell body ----------------
// gates(b, n') = A(b,:) . W(n',:), n' = h*4 + gate (gate-interleaved weights).
// mfma(W_frag, A_frag): lane's f32x4 = {i,f,g,o} of one (b,h) cell.
// MODE 0: A = [x(t) | h1(t-1)], K=1088, writes h1(t).
// MODE 1: A = [h1(t) | h2(t-1)], K=2048, writes h2(t) + y(t).
// LDS swizzle: stored kslot s at row r holds source kslot s ^ ((r>>1)&3)
// (uniform 2-way banks, R4-verified: conflicts 6.8M -> 393K). Both sides.

template <int MODE>
__device__ __forceinline__ void gemm_cell_body(
    int tm, int tn, int t,
    const bf16* __restrict__ P0, const bf16* __restrict__ P1,
    const bf16* __restrict__ Wt, const float* __restrict__ bperm,
    float* __restrict__ ct, bf16* __restrict__ Hout,
    const float* __restrict__ wp, const float* __restrict__ bp,
    float* __restrict__ y,
    bf16* As, bf16* Ws) {       // each [2][4096] elems (double-buffered 128x32)
  constexpr int KT = (MODE == 0) ? KL1 : KL2;
  constexpr int NT = KT / 32;

  int tid = threadIdx.x;
  int lane = tid & 63;
  int w = tid >> 6;
  int wg = (w & 1) << 6;      // gate-dim quadrant
  int wb = (w >> 1) << 6;     // batch-dim quadrant

  f32x4 acc[4][4];
  #pragma unroll
  for (int mw = 0; mw < 4; ++mw)
    #pragma unroll
    for (int nb = 0; nb < 4; ++nb) acc[mw][nb] = (f32x4){0.f, 0.f, 0.f, 0.f};

  // staging: LDS slot s=tid (+256) -> row = s>>2, stored kslot = s&3.
  // source kslot = (s&3) ^ ((row>>1)&3)   [inverse of read swizzle]
  int r0 = tid >> 2, r1 = (256 + tid) >> 2;
  int kc0 = (((tid & 3) ^ ((r0 >> 1) & 3)) << 3);
  int kc1 = (((tid & 3) ^ ((r1 >> 1) & 3)) << 3);
  int dst0 = (tid & ~63) * 8;
  int dst1 = 2048 + dst0;

  auto aptr = [&](int row, int gk) -> const bf16* {
    if constexpr (MODE == 0) {
      return (gk < 64) ? (P0 + ((size_t)(tm + row) * TT + t) * 64 + gk)
                       : (P1 + (size_t)(tm + row) * 1024 + (gk - 64));
    } else {
      return (gk < 1024) ? (P0 + (size_t)(tm + row) * 1024 + gk)
                         : (P1 + (size_t)(tm + row) * 1024 + (gk - 1024));
    }
  };
  auto stage = [&](int kt, int off) {
    int gk0 = kt * 32 + kc0, gk1 = kt * 32 + kc1;
    gload16(aptr(r0, gk0), As + off + dst0);
    gload16(aptr(r1, gk1), As + off + dst1);
    gload16(Wt + (size_t)(tn + r0) * KT + gk0, Ws + off + dst0);
    gload16(Wt + (size_t)(tn + r1) * KT + gk1, Ws + off + dst1);
  };

  // prologue: stage kt=0 into buffer half 0
  stage(0, 0);
  __syncthreads();

  int lrow = lane & 15;
  // read: logical kslot K = lane>>4 at row base+lrow -> stored K ^ ((lrow>>1)&3)
  int klocal = ((((lane >> 4) ^ (lrow >> 1)) & 3) << 3);

  for (int kt = 0; kt < NT; ++kt) {
    int cur = (kt & 1) << 12;          // 0 or 4096 elems
    if (kt + 1 < NT) stage(kt + 1, 4096 - cur);
    SB();  // keep prefetch issue ahead of compute

    bf16x8 af[4], wf[4];
    #pragma unroll
    for (int nb = 0; nb < 4; ++nb)
      af[nb] = *reinterpret_cast<const bf16x8*>(&As[cur + (wb + nb * 16 + lrow) * 32 + klocal]);
    #pragma unroll
    for (int mw = 0; mw < 4; ++mw)
      wf[mw] = *reinterpret_cast<const bf16x8*>(&Ws[cur + (wg + mw * 16 + lrow) * 32 + klocal]);

    __builtin_amdgcn_s_setprio(1);
    #pragma unroll
    for (int mw = 0; mw < 4; ++mw)
      #pragma unroll
      for (int nb = 0; nb < 4; ++nb)
        acc[mw][nb] = __builtin_amdgcn_mfma_f32_16x16x32_bf16(wf[mw], af[nb], acc[mw][nb], 0, 0, 0);
    __builtin_amdgcn_s_setprio(0);

    __syncthreads();  // drains prefetch vmcnt; next buffer ready
  }

  // ---- fused cell epilogue (hst reuses buf0: its reads fenced earlier) ----
  bf16* hst = As + w * 1024;          // 64 b x 16 h per wave
  int u = lane >> 4;                  // h sub-index
  int bl = lane & 15;                 // batch sub-index
  int hwave = (tn + wg) >> 2;         // wave's global h base
  float yp[4] = {0.f, 0.f, 0.f, 0.f};

  #pragma unroll
  for (int mw = 0; mw < 4; ++mw) {
    int hg = hwave + mw * 4 + u;
    f32x4 bv = *reinterpret_cast<const f32x4*>(&bperm[hg * 4]);
    float wph = 0.f;
    if constexpr (MODE == 1) wph = wp[hg];
    #pragma unroll
    for (int nb = 0; nb < 4; ++nb) {
      int bg = tm + wb + nb * 16 + bl;
      float gi = acc[mw][nb][0] + bv[0];
      float gf = acc[mw][nb][1] + bv[1];
      float gg = acc[mw][nb][2] + bv[2];
      float go = acc[mw][nb][3] + bv[3];
      float* cp_ = ct + (size_t)hg * BB + bg;
      float c = *cp_;
      float cn = sigm(gf) * c + sigm(gi) * tanhf(gg);
      float hn = sigm(go) * tanhf(cn);
      *cp_ = cn;
      hst[(nb * 16 + bl) * 16 + mw * 4 + u] = (bf16)hn;
      if constexpr (MODE == 1) yp[nb] += hn * wph;
    }
  }

  asm volatile("s_waitcnt lgkmcnt(0)" ::: "memory");
  SB();

  // coalesced Hout write-out (LD = 1024)
  #pragma unroll
  for (int q = 0; q < 2; ++q) {
    int chunk = q * 64 + lane;
    int bl2 = chunk >> 1, half = chunk & 1;
    bf16x8 v = *reinterpret_cast<const bf16x8*>(&hst[bl2 * 16 + half * 8]);
    int bg = tm + wb + bl2;
    *reinterpret_cast<bf16x8*>(&Hout[(size_t)bg * 1024 + hwave + half * 8]) = v;
  }

  if constexpr (MODE == 1) {
    #pragma unroll
    for (int nb = 0; nb < 4; ++nb) {
      float s = yp[nb];
      s += __shfl_xor(s, 16);
      s += __shfl_xor(s, 32);
      if (lane < 16)
        atomicAdd(&y[(size_t)(tm + wb + nb * 16 + lane) * TT + t], s);
    }
  } else {
    // init y[:, t] = b_proj before D_t's layer-2 atomics (blocks with tn==0)
    if (tn == 0 && tid < 128) y[(size_t)(tm + tid) * TT + t] = bp[0];
  }
}

// Grid 768: bids [0,512) = L2(t) (128x128 tiles, 64 K-tiles);
// bids [512,768) = L1(t+1), each doing TWO 128-wide tn tiles (68 K-tile-equiv)
// so block durations match. only_l1: grid 256, all blocks L1(t2+1).
__global__ __launch_bounds__(256, 4) void step_kernel(
    const bf16* __restrict__ H1in, const bf16* __restrict__ H2in,
    bf16* __restrict__ H1out, bf16* __restrict__ H2out,
    const bf16* __restrict__ X,
    const bf16* __restrict__ W0, const bf16* __restrict__ W1,
    const float* __restrict__ b0p, const float* __restrict__ b1p,
    float* __restrict__ c1t, float* __restrict__ c2t,
    const float* __restrict__ wp, const float* __restrict__ bp,
    float* __restrict__ y, int t2, int only_l1) {
  __shared__ alignas(16) bf16 As[2 * 4096];
  __shared__ alignas(16) bf16 Ws[2 * 4096];
  int bid = (int)blockIdx.x;
  if (only_l1 || bid >= 512) {
    int vb = only_l1 ? bid : bid - 512;       // [0,256)
    int t1 = t2 + 1;
    if (t1 >= TT) return;
    int swz = (vb & 7) * 32 + (vb >> 3);      // XCD-aware, bijective (256%8==0)
    int tm  = (swz & 15) << 7;
    int tn0 = (swz >> 4) << 8;                // pair base: two 128-tiles
    gemm_cell_body<0>(tm, tn0, t1, X, H1in, W0, b0p, c1t, H1out, nullptr, bp, y, As, Ws);
    __syncthreads();                          // hst reads done before restaging
    gemm_cell_body<0>(tm, tn0 + 128, t1, X, H1in, W0, b0p, c1t, H1out, nullptr, bp, y, As, Ws);
  } else {
    int swz = (bid & 7) * 64 + (bid >> 3);    // bijective (512%8==0)
    int tm = (swz & 15) << 7;
    int tn = (swz >> 4) << 7;
    gemm_cell_body<1>(tm, tn, t2, H1in, H2in, W1, b1p, c2t, H2out, wp, nullptr, y, As, Ws);
  }
}

// ---------------- launch ----------------

extern "C" void kernel_launch(void* const* d_in, const int* in_sizes, int n_in,
                              void* d_out, int out_size, void* d_ws, size_t ws_size,
                              hipStream_t stream) {
  const float* dec   = (const float*)d_in[0];
  const float* ty    = (const float*)d_in[1];
  const float* enc_h = (const float*)d_in[2];
  const float* enc_c = (const float*)d_in[3];
  const float* lec   = (const float*)d_in[4];
  const int*   gid   = (const int*)d_in[5];
  const int*   cp    = (const int*)d_in[6];
  const int*   cct   = (const int*)d_in[7];
  const int*   cpt   = (const int*)d_in[8];
  const int*   ccl   = (const int*)d_in[9];
  const float* gemb  = (const float*)d_in[10];
  const float* ep    = (const float*)d_in[11];
  const float* ect   = (const float*)d_in[12];
  const float* ept   = (const float*)d_in[13];
  const float* ecl   = (const float*)d_in[14];
  const float* Wih0  = (const float*)d_in[15];
  const float* Whh0  = (const float*)d_in[16];
  const float* b0    = (const float*)d_in[17];
  const float* Wih1  = (const float*)d_in[18];
  const float* Whh1  = (const float*)d_in[19];
  const float* b1    = (const float*)d_in[20];
  const float* wp    = (const float*)d_in[21];
  const float* bp    = (const float*)d_in[22];
  float* y = (float*)d_out;

  char* ws = (char*)d_ws;
  bf16* W0    = (bf16*)ws;  ws += (size_t)NG * KL1 * 2;      //  8.9 MB
  bf16* W1    = (bf16*)ws;  ws += (size_t)NG * KL2 * 2;      // 16.8 MB
  bf16* X     = (bf16*)ws;  ws += (size_t)BB * TT * 64 * 2;  // 25.2 MB
  bf16* H1a   = (bf16*)ws;  ws += (size_t)BB * 1024 * 2;     //  4.2 MB each
  bf16* H1b   = (bf16*)ws;  ws += (size_t)BB * 1024 * 2;
  bf16* H2a   = (bf16*)ws;  ws += (size_t)BB * 1024 * 2;
  bf16* H2b   = (bf16*)ws;  ws += (size_t)BB * 1024 * 2;
  float* c1t  = (float*)ws; ws += (size_t)BB * 1024 * 4;     //  8.4 MB
  float* c2t  = (float*)ws; ws += (size_t)BB * 1024 * 4;     //  8.4 MB
  float* b0p  = (float*)ws; ws += (size_t)NG * 4;
  float* b1p  = (float*)ws; ws += (size_t)NG * 4;

  build_w0<<<(NG * KL1 + 255) / 256, 256, 0, stream>>>(Wih0, Whh0, W0);
  build_w1<<<(NG * KL2 + 255) / 256, 256, 0, stream>>>(Wih1, Whh1, W1);
  perm_bias<<<NG / 256, 256, 0, stream>>>(b0, b1, b0p, b1p);
  build_x<<<(BB * TT + 255) / 256, 256, 0, stream>>>(dec, ty, lec, gid, cp, cct, cpt, ccl,
                                                     gemb, ep, ect, ept, ecl, X);
  init_state<<<(BB * 1024) / 256, 256, 0, stream>>>(enc_h, enc_c, H1b, H2b, c1t, c2t);

  // prologue: L1(0) alone (grid 256). h1(t) in H1[t&1]; h2(t) in H2[t&1].
  step_kernel<<<256, 256, 0, stream>>>(H1b, nullptr, H1a, nullptr, X, W0, W1,
                                       b0p, b1p, c1t, c2t, wp, bp, y, -1, 1);
  for (int t = 0; t < TT; ++t) {
    bf16* h1i = (t & 1) ? H1b : H1a;
    bf16* h1o = (t & 1) ? H1a : H1b;
    bf16* h2i = (t & 1) ? H2a : H2b;
    bf16* h2o = (t & 1) ? H2b : H2a;
    step_kernel<<<768, 256, 0, stream>>>(h1i, h2i, h1o, h2o, X, W0, W1,
                                         b0p, b1p, c1t, c2t, wp, bp, y, t, 0);
  }
}